// Round 2
// baseline (573.939 us; speedup 1.0000x reference)
//
#include <hip/hip_runtime.h>
#include <math.h>

// Problem constants (reference file)
#define NPTS   500000
#define CIN    16
#define COUT   64
#define GRID_W 256
#define NCELL  65536

// ws layout (bytes)
#define WS_HIST   0                      // 65536 u32  (256 KB)
#define WS_CUR    262144                 // 65536 u32 scatter cursors (256 KB)
#define WS_STARTS 524288                 // 65536 u32 segment starts (256 KB)
#define WS_RANK   786432                 // 500000 i32 rank[p] (2 MB)
#define WS_WPK    2883456                // 18432 f16 frag-packed weights (36864 B)
#define WS_PART   2920320                // 256 u32 block partials (1 KB)
#define WS_FEAT   2921344                // 500000*64 f16 feature rows (64 MB)
                                         //   (first 1 MB doubles as u16 cell ids,
                                         //    consumed by scatter before mlp writes)
#define WS_NEED   (WS_FEAT + (size_t)NPTS * COUT * 2)

#define PT_BLOCKS ((NPTS + 255) / 256)   // 1954 (aux kernels, 256 thr)
#define MB_BLOCKS ((NPTS + 511) / 512)   // 977  (main kernel, 512 thr)

#define W_HALFS   18432                  // (28+8) frags * 64 lanes * 8 halfs
#define W1_FRAGS  28                     // 7 k-steps * 4 ch-tiles

typedef _Float16 f16x8 __attribute__((ext_vector_type(8)));
typedef _Float16 f16x2 __attribute__((ext_vector_type(2)));
typedef float    f32x4 __attribute__((ext_vector_type(4)));

__device__ __forceinline__ f16x2 pk2(float a, float b) {
    auto r = __builtin_amdgcn_cvt_pkrtz(a, b);   // v_cvt_pkrtz_f16_f32
    union { decltype(r) x; f16x2 y; } u; u.x = r;
    return u.y;
}

__device__ __forceinline__ int cell_index(float v) {
    float nf = fminf(fmaxf((v + 1.0f) * 0.5f, 0.0f), 1.0f);
    int i = (int)floorf(nf * 256.0f);
    return i > 255 ? 255 : i;
}

__device__ __forceinline__ int flat_of(const float* pos, int p, int a1, int a2) {
    float pa1 = pos[p * 3 + a1];
    float pa2 = pos[p * 3 + a2];
    return cell_index(pa1) * GRID_W + cell_index(pa2);
}

// K0: fused weight-pack (frag order; A/B frag layouts are symmetric so this
// packing serves the swapped-operand GEMM unchanged) + histogram + cell ids.
__global__ void pack_hist_kernel(const float* __restrict__ W1,
                                 const float* __restrict__ W2,
                                 const float* __restrict__ pos,
                                 const int* __restrict__ ax1p,
                                 const int* __restrict__ ax2p,
                                 _Float16* __restrict__ wpk,
                                 unsigned int* __restrict__ hist,
                                 unsigned short* __restrict__ cellp)
{
    int i = blockIdx.x * 256 + threadIdx.x;
    if (i < W_HALFS) {
        int j = i & 7, lane = (i >> 3) & 63, f = i >> 9;
        int k  = ((f < W1_FRAGS) ? (f >> 2) : ((f - W1_FRAGS) >> 2)) * 32 + ((lane >> 4) << 3) + j;
        int ch = (f & 3) * 16 + (lane & 15);
        float v;
        if (f < W1_FRAGS) v = (k < 208) ? W1[k * 64 + ch] : 0.0f;
        else              v = W2[k * 64 + ch];
        wpk[i] = (_Float16)v;
    }
    if (i < NPTS) {
        int flat = flat_of(pos, i, ax1p[0], ax2p[0]);
        atomicAdd(&hist[flat], 1u);
        if (cellp) cellp[i] = (unsigned short)flat;
    }
}

// K1a: per-256-cell-chunk sums (coalesced)
__global__ void scan_sum_kernel(const unsigned int* __restrict__ hist,
                                unsigned int* __restrict__ part)
{
    __shared__ unsigned int sc[256];
    const int t = threadIdx.x;
    sc[t] = hist[blockIdx.x * 256 + t];
    __syncthreads();
    for (int off = 128; off > 0; off >>= 1) {
        if (t < off) sc[t] += sc[t + off];
        __syncthreads();
    }
    if (t == 0) part[blockIdx.x] = sc[0];
}

// K1b: exclusive scan of the 256 partials (single tiny block)
__global__ void scan_top_kernel(unsigned int* __restrict__ part)
{
    __shared__ unsigned int sc[256];
    const int t = threadIdx.x;
    unsigned int v = part[t];
    sc[t] = v;
    __syncthreads();
    for (int off = 1; off < 256; off <<= 1) {
        unsigned int add = (t >= off) ? sc[t - off] : 0u;
        __syncthreads();
        sc[t] += add;
        __syncthreads();
    }
    part[t] = sc[t] - v;   // exclusive
}

// K1c: per-chunk exclusive scan + chunk base -> cursors & starts (coalesced)
__global__ void scan_apply_kernel(const unsigned int* __restrict__ hist,
                                  const unsigned int* __restrict__ part,
                                  unsigned int* __restrict__ cur,
                                  unsigned int* __restrict__ starts)
{
    __shared__ unsigned int sc[256];
    const int t = threadIdx.x;
    unsigned int v = hist[blockIdx.x * 256 + t];
    sc[t] = v;
    __syncthreads();
    for (int off = 1; off < 256; off <<= 1) {
        unsigned int add = (t >= off) ? sc[t - off] : 0u;
        __syncthreads();
        sc[t] += add;
        __syncthreads();
    }
    unsigned int e = sc[t] - v + part[blockIdx.x];
    cur[blockIdx.x * 256 + t]    = e;
    starts[blockIdx.x * 256 + t] = e;
}

// K2: assign each point its rank (= destination slot in cell-sorted order).
__global__ void scatter_kernel(const unsigned short* __restrict__ cellp,
                               unsigned int* __restrict__ cur,
                               int* __restrict__ rank)
{
    int p = blockIdx.x * 256 + threadIdx.x;
    if (p >= NPTS) return;
    int flat = cellp[p];
    rank[p] = (int)atomicAdd(&cur[flat], 1u);
}

// K3: MFMA MLP, swapped operands (weights = A-frag, generated X^T = B-frag).
// D is channel-major: lane (g,n) holds channels {16c+4g+r} of point n.
// 1 tile (16 points) per pass -> acc is 16 regs; launch_bounds(512,6) targets
// <=85 regs so 3 blocks/CU (LDS 53248 B) can be resident = 24 waves/CU.
__global__ __launch_bounds__(512, 6)
void mlp_mfma_kernel(const float* __restrict__ pos,
                     const float* __restrict__ feats,
                     const _Float16* __restrict__ wpk,
                     const float* __restrict__ b1,
                     const float* __restrict__ ln_g,
                     const float* __restrict__ ln_b,
                     const int*   __restrict__ ax1p,
                     const int*   __restrict__ ax2p,
                     const int*   __restrict__ rank,
                     _Float16* __restrict__ featbuf,
                     float* __restrict__ out,
                     int use_feat)
{
    __shared__ __align__(16) _Float16 WF[W_HALFS];   // 36864 B
    __shared__ __align__(16) _Float16 PS[8 * 1024];  // 16384 B (per-wave 16x64, swizzled)

    // stage frag-packed weights (coalesced 16B copies)
    {
        const uint4* src = (const uint4*)wpk;
        uint4* dst = (uint4*)WF;
        for (int i = threadIdx.x; i < W_HALFS / 8; i += 512) dst[i] = src[i];
    }

    const int lane = threadIdx.x & 63;
    const int wv   = threadIdx.x >> 6;
    const int g    = lane >> 4;        // quad
    const int n    = lane & 15;        // point-within-tile (B-col / D-col)
    char* Pw = (char*)(PS + wv * 1024);          // 2048 B per wave
    const unsigned sw = (unsigned)((n & 7) << 4);  // XOR swizzle (byte, 16B unit)

    const int wbase = blockIdx.x * 512 + wv * 64;

    // lane-constant PE base frequency: f0 = (8g+16)&31 for every s
    const float base  = 1.57079632679489662f *
                        exp2f((float)((8 * g + 16) & 31) * 0.03125f);
    const float RSTEP = 1.02189714865411668f;    // 2^(1/32)
    const float PI2   = 1.57079632679489662f;

    __syncthreads();   // WF visible

    #pragma unroll 1
    for (int t = 0; t < 4; ++t) {
        const int st = wbase + t * 16 + n;
        const int p  = (st < NPTS) ? st : 0;
        const float px = pos[3 * p + 0];
        const float py = pos[3 * p + 1];
        const float pz = pos[3 * p + 2];

        // feats prefetch (B-frag rows for s=0, g<2)
        float4 fA, fB;
        if (g < 2) {
            const float4* fr = (const float4*)(feats + (size_t)p * CIN + g * 8);
            fA = fr[0]; fB = fr[1];
        }

        // ---- GEMM1: acc[c] = H[ch 16c+4g+r][point n], K = 224 ------------
        f32x4 acc[4];
        #pragma unroll
        for (int c = 0; c < 4; ++c) acc[c] = (f32x4){0.0f, 0.0f, 0.0f, 0.0f};

        #pragma unroll
        for (int s = 0; s < 7; ++s) {
            union { f16x8 v; f16x2 h[4]; } U;
            const int k0 = s * 32 + g * 8;
            if (s == 0 && g < 2) {               // feats (prefetched)
                U.h[0] = pk2(fA.x, fA.y); U.h[1] = pk2(fA.z, fA.w);
                U.h[2] = pk2(fB.x, fB.y); U.h[3] = pk2(fB.z, fB.w);
            } else if (k0 >= 208) {              // zero pad (s==6, g>=2)
                #pragma unroll
                for (int q = 0; q < 4; ++q) U.h[q] = pk2(0.0f, 0.0f);
            } else {                             // PE: sin with phase in FMA chain
                const int   e    = k0 - 16;
                const float pv   = (e < 64) ? px : ((e < 128) ? py : pz);
                const float off  = (e & 32) ? PI2 : 0.0f;
                const float offc = (e & 32) ? (PI2 * (1.0f - RSTEP)) : 0.0f;
                float a = fmaf(pv, base, off);
                #pragma unroll
                for (int q = 0; q < 4; ++q) {
                    float v0 = __sinf(a); a = fmaf(a, RSTEP, offc);
                    float v1 = __sinf(a); a = fmaf(a, RSTEP, offc);
                    U.h[q] = pk2(v0, v1);
                }
            }
            #pragma unroll
            for (int c = 0; c < 4; ++c) {
                f16x8 af = ((const f16x8*)WF)[(s * 4 + c) * 64 + lane];
                acc[c] = __builtin_amdgcn_mfma_f32_16x16x32_f16(af, U.v, acc[c], 0, 0, 0);
            }
        }

        // ---- LN stats (lane-local 16 + 2 shuffles) ------------------------
        float s1 = 0.0f, s2 = 0.0f;
        #pragma unroll
        for (int c = 0; c < 4; ++c) {
            f32x4 b1q = *(const f32x4*)(b1 + 16 * c + 4 * g);
            #pragma unroll
            for (int r = 0; r < 4; ++r) {
                float x = acc[c][r] + b1q[r];
                acc[c][r] = x;
                s1 += x; s2 += x * x;
            }
        }
        s1 += __shfl_xor(s1, 16); s2 += __shfl_xor(s2, 16);
        s1 += __shfl_xor(s1, 32); s2 += __shfl_xor(s2, 32);
        const float mu   = s1 * (1.0f / 64.0f);
        const float var  = s2 * (1.0f / 64.0f) - mu * mu;
        const float rstd = __builtin_amdgcn_rsqf(var + 1e-5f);

        // ---- GELU -> Pw (b64 swizzled writes) -----------------------------
        #pragma unroll
        for (int c = 0; c < 4; ++c) {
            f32x4 gq = *(const f32x4*)(ln_g + 16 * c + 4 * g);
            f32x4 bq = *(const f32x4*)(ln_b + 16 * c + 4 * g);
            float gv[4];
            #pragma unroll
            for (int r = 0; r < 4; ++r) {
                float x  = (acc[c][r] - mu) * rstd * gq[r] + bq[r];
                float u  = x * (0.7978845608028654f + 0.0356774081363001f * x * x);
                float e  = __expf(2.0f * u);
                float th = 1.0f - 2.0f * __builtin_amdgcn_rcpf(e + 1.0f);
                gv[r] = 0.5f * x * (1.0f + th);
            }
            union { f16x2 h[2]; uint2 u2; } W;
            W.h[0] = pk2(gv[0], gv[1]);
            W.h[1] = pk2(gv[2], gv[3]);
            *(uint2*)(Pw + n * 128 + (((unsigned)(32 * c + 8 * g)) ^ sw)) = W.u2;
        }

        // ---- GEMM2: acc2[c] = O[ch 16c+4g+r][point n] ---------------------
        f32x4 acc2[4];
        #pragma unroll
        for (int c = 0; c < 4; ++c) acc2[c] = (f32x4){0.0f, 0.0f, 0.0f, 0.0f};
        #pragma unroll
        for (int s = 0; s < 2; ++s) {
            f16x8 bf2 = *(const f16x8*)(Pw + n * 128 + (((unsigned)(64 * s + 16 * g)) ^ sw));
            #pragma unroll
            for (int c = 0; c < 4; ++c) {
                f16x8 af = ((const f16x8*)WF)[(W1_FRAGS + s * 4 + c) * 64 + lane];
                acc2[c] = __builtin_amdgcn_mfma_f32_16x16x32_f16(af, bf2, acc2[c], 0, 0, 0);
            }
        }

        if (use_feat) {
            // stage D2 -> Pw (b64 swizzled), then full-line scattered stores
            #pragma unroll
            for (int c = 0; c < 4; ++c) {
                union { f16x2 h[2]; uint2 u2; } W;
                W.h[0] = pk2(acc2[c][0], acc2[c][1]);
                W.h[1] = pk2(acc2[c][2], acc2[c][3]);
                *(uint2*)(Pw + n * 128 + (((unsigned)(32 * c + 8 * g)) ^ sw)) = W.u2;
            }
            // 8 lanes per row x 16B: each store instr covers 8 full 128B lines
            #pragma unroll
            for (int h = 0; h < 2; ++h) {
                const int row = h * 8 + (lane >> 3);
                const int gs  = wbase + t * 16 + row;
                if (gs < NPTS) {
                    const uint4 v = *(const uint4*)(Pw + row * 128 +
                        (((unsigned)((lane & 7) * 16)) ^ ((unsigned)((row & 7) << 4))));
                    *(uint4*)(featbuf + (size_t)rank[gs] * COUT + (lane & 7) * 8) = v;
                }
            }
        } else {
            // fallback: direct fp32 atomics (correctness path, not perf)
            if (st < NPTS) {
                const int cellr = flat_of(pos, p, ax1p[0], ax2p[0]);
                #pragma unroll
                for (int c = 0; c < 4; ++c)
                    #pragma unroll
                    for (int r = 0; r < 4; ++r)
                        unsafeAtomicAdd(&out[(size_t)(16 * c + 4 * g + r) * NCELL + cellr],
                                        acc2[c][r]);
            }
        }
    }
}

// K4: per-cell dense reduce. 1 cell per wave, 4 predicated independent loads
// (no serial tail); block = 1024 thr = 16 waves = 16 cells; 4096 blocks.
__global__ __launch_bounds__(1024)
void reduce_kernel(const _Float16* __restrict__ featbuf,
                   const unsigned int* __restrict__ starts,
                   const unsigned int* __restrict__ hist,
                   const float* __restrict__ b2,
                   float* __restrict__ out)
{
    __shared__ float R[16][66];
    const int lane  = threadIdx.x & 63;
    const int wv    = threadIdx.x >> 6;    // 0..15 = cell-within-block
    const int cbase = blockIdx.x * 16;
    const float b2v = b2[lane];

    const int cell = cbase + wv;
    const unsigned int s0  = starts[cell];
    const unsigned int cnt = hist[cell];

    float a0 = 0.0f, a1 = 0.0f, a2 = 0.0f, a3 = 0.0f;
    for (unsigned int k = 0; k < cnt; k += 4) {
        unsigned int i0 = s0 + k;
        unsigned int i1 = i0 + 1 < (unsigned)NPTS ? i0 + 1 : (unsigned)(NPTS - 1);
        unsigned int i2 = i0 + 2 < (unsigned)NPTS ? i0 + 2 : (unsigned)(NPTS - 1);
        unsigned int i3 = i0 + 3 < (unsigned)NPTS ? i0 + 3 : (unsigned)(NPTS - 1);
        float v0 = (float)featbuf[(size_t)i0 * COUT + lane];
        float v1 = (float)featbuf[(size_t)i1 * COUT + lane];
        float v2 = (float)featbuf[(size_t)i2 * COUT + lane];
        float v3 = (float)featbuf[(size_t)i3 * COUT + lane];
        a0 += v0;
        a1 += (k + 1 < cnt) ? v1 : 0.0f;
        a2 += (k + 2 < cnt) ? v2 : 0.0f;
        a3 += (k + 3 < cnt) ? v3 : 0.0f;
    }
    float m = (a0 + a1) + (a2 + a3);
    R[wv][lane] = m / fmaxf((float)cnt, 1.0f) + (cnt ? b2v : 0.0f);
    __syncthreads();

    // store: thread t -> out[ch = t>>4][cbase + (t&15)]; 64B contiguous per ch
    const int ch = threadIdx.x >> 4;
    const int ci = threadIdx.x & 15;
    out[ch * NCELL + cbase + ci] = R[ci][ch];
}

// K5 (fallback only): divide by counts + add b2 (guarded for empty cells)
__global__ void finalize_kernel(float* __restrict__ out,
                                const unsigned int* __restrict__ hist,
                                const float* __restrict__ b2)
{
    int t = blockIdx.x * 256 + threadIdx.x;
    int cell = t & (NCELL - 1);
    int ch   = t >> 16;
    float c  = (float)hist[cell];
    out[t] = out[t] / fmaxf(c, 1.0f) + ((c > 0.0f) ? b2[ch] : 0.0f);
}

extern "C" void kernel_launch(void* const* d_in, const int* in_sizes, int n_in,
                              void* d_out, int out_size, void* d_ws, size_t ws_size,
                              hipStream_t stream) {
    (void)in_sizes; (void)n_in; (void)out_size;
    const float* pos   = (const float*)d_in[0];
    const float* feats = (const float*)d_in[1];
    const float* W1    = (const float*)d_in[2];
    const float* b1    = (const float*)d_in[3];
    const float* ln_g  = (const float*)d_in[4];
    const float* ln_b  = (const float*)d_in[5];
    const float* W2    = (const float*)d_in[6];
    const float* b2    = (const float*)d_in[7];
    const int*   ax1   = (const int*)d_in[8];
    const int*   ax2   = (const int*)d_in[9];

    char* ws = (char*)d_ws;
    unsigned int*   hist   = (unsigned int*)(ws + WS_HIST);
    unsigned int*   cur    = (unsigned int*)(ws + WS_CUR);
    unsigned int*   starts = (unsigned int*)(ws + WS_STARTS);
    int*            rank   = (int*)(ws + WS_RANK);
    _Float16*       wpk    = (_Float16*)(ws + WS_WPK);
    unsigned int*   part   = (unsigned int*)(ws + WS_PART);
    _Float16*       featbf = (_Float16*)(ws + WS_FEAT);
    unsigned short* cell16 = (unsigned short*)(ws + WS_FEAT);  // overlay, pre-mlp

    float* out = (float*)d_out;
    const int use_feat = (ws_size >= WS_NEED) ? 1 : 0;

    hipMemsetAsync(hist, 0, NCELL * sizeof(unsigned int), stream);
    if (!use_feat)
        hipMemsetAsync(d_out, 0, (size_t)COUT * NCELL * sizeof(float), stream);

    pack_hist_kernel<<<PT_BLOCKS, 256, 0, stream>>>(
        W1, W2, pos, ax1, ax2, wpk, hist,
        use_feat ? cell16 : (unsigned short*)nullptr);
    if (use_feat) {
        scan_sum_kernel<<<256, 256, 0, stream>>>(hist, part);
        scan_top_kernel<<<1, 256, 0, stream>>>(part);
        scan_apply_kernel<<<256, 256, 0, stream>>>(hist, part, cur, starts);
        scatter_kernel<<<PT_BLOCKS, 256, 0, stream>>>(cell16, cur, rank);
    }
    mlp_mfma_kernel<<<MB_BLOCKS, 512, 0, stream>>>(
        pos, feats, wpk, b1, ln_g, ln_b, ax1, ax2, rank, featbf, out, use_feat);
    if (use_feat)
        reduce_kernel<<<NCELL / 16, 1024, 0, stream>>>(featbf, starts, hist, b2, out);
    else
        finalize_kernel<<<(COUT * NCELL) / 256, 256, 0, stream>>>(out, hist, b2);
}

// Round 3
// 232.032 us; speedup vs baseline: 2.4735x; 2.4735x over previous
//
#include <hip/hip_runtime.h>
#include <math.h>

// Problem constants (reference file)
#define NPTS   500000
#define CIN    16
#define COUT   64
#define GRID_W 256
#define NCELL  65536

// ws layout (bytes)
#define WS_HIST   0                      // 65536 u32  (256 KB)
#define WS_CUR    262144                 // 65536 u32 scatter cursors (256 KB)
#define WS_STARTS 524288                 // 65536 u32 segment starts (256 KB)
#define WS_RANK   786432                 // 500000 i32 rank[p] (2 MB)
#define WS_WPK    2883456                // 18432 f16 frag-packed weights (36864 B)
#define WS_PART   2920320                // 256 u32 block partials (1 KB)
#define WS_FEAT   2921344                // 500000*64 f16 feature rows (64 MB)
                                         //   (first 1 MB doubles as u16 cell ids,
                                         //    consumed by scatter before mlp writes)
#define WS_NEED   (WS_FEAT + (size_t)NPTS * COUT * 2)

#define PT_BLOCKS ((NPTS + 255) / 256)   // 1954 (aux kernels, 256 thr)
#define MB_BLOCKS ((NPTS + 511) / 512)   // 977  (main kernel, 512 thr)

#define W_HALFS   18432                  // (28+8) frags * 64 lanes * 8 halfs
#define W1_FRAGS  28                     // 7 k-steps * 4 ch-tiles

typedef _Float16 f16x8 __attribute__((ext_vector_type(8)));
typedef _Float16 f16x2 __attribute__((ext_vector_type(2)));
typedef float    f32x4 __attribute__((ext_vector_type(4)));

__device__ __forceinline__ f16x2 pk2(float a, float b) {
    auto r = __builtin_amdgcn_cvt_pkrtz(a, b);   // v_cvt_pkrtz_f16_f32
    union { decltype(r) x; f16x2 y; } u; u.x = r;
    return u.y;
}

__device__ __forceinline__ int cell_index(float v) {
    float nf = fminf(fmaxf((v + 1.0f) * 0.5f, 0.0f), 1.0f);
    int i = (int)floorf(nf * 256.0f);
    return i > 255 ? 255 : i;
}

__device__ __forceinline__ int flat_of(const float* pos, int p, int a1, int a2) {
    float pa1 = pos[p * 3 + a1];
    float pa2 = pos[p * 3 + a2];
    return cell_index(pa1) * GRID_W + cell_index(pa2);
}

// K0: fused weight-pack (frag order; A/B frag layouts are symmetric so this
// packing serves the swapped-operand GEMM unchanged) + histogram + cell ids.
__global__ void pack_hist_kernel(const float* __restrict__ W1,
                                 const float* __restrict__ W2,
                                 const float* __restrict__ pos,
                                 const int* __restrict__ ax1p,
                                 const int* __restrict__ ax2p,
                                 _Float16* __restrict__ wpk,
                                 unsigned int* __restrict__ hist,
                                 unsigned short* __restrict__ cellp)
{
    int i = blockIdx.x * 256 + threadIdx.x;
    if (i < W_HALFS) {
        int j = i & 7, lane = (i >> 3) & 63, f = i >> 9;
        int k  = ((f < W1_FRAGS) ? (f >> 2) : ((f - W1_FRAGS) >> 2)) * 32 + ((lane >> 4) << 3) + j;
        int ch = (f & 3) * 16 + (lane & 15);
        float v;
        if (f < W1_FRAGS) v = (k < 208) ? W1[k * 64 + ch] : 0.0f;
        else              v = W2[k * 64 + ch];
        wpk[i] = (_Float16)v;
    }
    if (i < NPTS) {
        int flat = flat_of(pos, i, ax1p[0], ax2p[0]);
        atomicAdd(&hist[flat], 1u);
        if (cellp) cellp[i] = (unsigned short)flat;
    }
}

// K1a: per-256-cell-chunk sums (coalesced)
__global__ void scan_sum_kernel(const unsigned int* __restrict__ hist,
                                unsigned int* __restrict__ part)
{
    __shared__ unsigned int sc[256];
    const int t = threadIdx.x;
    sc[t] = hist[blockIdx.x * 256 + t];
    __syncthreads();
    for (int off = 128; off > 0; off >>= 1) {
        if (t < off) sc[t] += sc[t + off];
        __syncthreads();
    }
    if (t == 0) part[blockIdx.x] = sc[0];
}

// K1b: exclusive scan of the 256 partials (single tiny block)
__global__ void scan_top_kernel(unsigned int* __restrict__ part)
{
    __shared__ unsigned int sc[256];
    const int t = threadIdx.x;
    unsigned int v = part[t];
    sc[t] = v;
    __syncthreads();
    for (int off = 1; off < 256; off <<= 1) {
        unsigned int add = (t >= off) ? sc[t - off] : 0u;
        __syncthreads();
        sc[t] += add;
        __syncthreads();
    }
    part[t] = sc[t] - v;   // exclusive
}

// K1c: per-chunk exclusive scan + chunk base -> cursors & starts (coalesced)
__global__ void scan_apply_kernel(const unsigned int* __restrict__ hist,
                                  const unsigned int* __restrict__ part,
                                  unsigned int* __restrict__ cur,
                                  unsigned int* __restrict__ starts)
{
    __shared__ unsigned int sc[256];
    const int t = threadIdx.x;
    unsigned int v = hist[blockIdx.x * 256 + t];
    sc[t] = v;
    __syncthreads();
    for (int off = 1; off < 256; off <<= 1) {
        unsigned int add = (t >= off) ? sc[t - off] : 0u;
        __syncthreads();
        sc[t] += add;
        __syncthreads();
    }
    unsigned int e = sc[t] - v + part[blockIdx.x];
    cur[blockIdx.x * 256 + t]    = e;
    starts[blockIdx.x * 256 + t] = e;
}

// K2: assign each point its rank (= destination slot in cell-sorted order).
__global__ void scatter_kernel(const unsigned short* __restrict__ cellp,
                               unsigned int* __restrict__ cur,
                               int* __restrict__ rank)
{
    int p = blockIdx.x * 256 + threadIdx.x;
    if (p >= NPTS) return;
    int flat = cellp[p];
    rank[p] = (int)atomicAdd(&cur[flat], 1u);
}

// K3: MFMA MLP, swapped operands (weights = A-frag, generated X^T = B-frag).
// D is channel-major: lane (g,n) holds channels {16c+4g+r} of point n.
// 2 tiles (32 points) per pass: acc[2][4] = 32 regs, halves LDS weight-read
// traffic vs 1-tile. launch_bounds(512,4) = 128-reg unified budget: NO spills
// (round-2's (512,6)=85-reg cap spilled catastrophically: 1.2 GB scratch).
__global__ __launch_bounds__(512, 4)
void mlp_mfma_kernel(const float* __restrict__ pos,
                     const float* __restrict__ feats,
                     const _Float16* __restrict__ wpk,
                     const float* __restrict__ b1,
                     const float* __restrict__ ln_g,
                     const float* __restrict__ ln_b,
                     const int*   __restrict__ ax1p,
                     const int*   __restrict__ ax2p,
                     const int*   __restrict__ rank,
                     _Float16* __restrict__ featbuf,
                     float* __restrict__ out,
                     int use_feat)
{
    __shared__ __align__(16) _Float16 WF[W_HALFS];   // 36864 B
    __shared__ __align__(16) _Float16 PS[8 * 2048];  // 32768 B (wave: 2 x 2048 B bufs)

    // stage frag-packed weights (coalesced 16B copies)
    {
        const uint4* src = (const uint4*)wpk;
        uint4* dst = (uint4*)WF;
        for (int i = threadIdx.x; i < W_HALFS / 8; i += 512) dst[i] = src[i];
    }

    const int lane = threadIdx.x & 63;
    const int wv   = threadIdx.x >> 6;
    const int g    = lane >> 4;        // quad
    const int n    = lane & 15;        // point-within-tile (B-col / D-col)
    char* Pw = (char*)(PS + wv * 2048);            // 4096 B per wave (2 bufs)
    const unsigned sw = (unsigned)((n & 7) << 4);  // XOR swizzle (byte, 16B unit)

    const int wbase = blockIdx.x * 512 + wv * 64;

    // lane-constant PE base frequency: f0 = (8g+16)&31 for every s
    const float base  = 1.57079632679489662f *
                        exp2f((float)((8 * g + 16) & 31) * 0.03125f);
    const float RSTEP = 1.02189714865411668f;    // 2^(1/32)
    const float PI2   = 1.57079632679489662f;

    __syncthreads();   // WF visible

    #pragma unroll 1
    for (int tp = 0; tp < 2; ++tp) {
        // ---- load 2 tiles' point data -------------------------------------
        float px[2], py[2], pz[2];
        f16x8 fH[2];
        #pragma unroll
        for (int u = 0; u < 2; ++u) {
            const int st = wbase + (tp * 2 + u) * 16 + n;
            const int p  = (st < NPTS) ? st : 0;
            px[u] = pos[3 * p + 0];
            py[u] = pos[3 * p + 1];
            pz[u] = pos[3 * p + 2];
            if (g < 2) {
                const float4* fr = (const float4*)(feats + (size_t)p * CIN + g * 8);
                float4 fa = fr[0], fb = fr[1];
                union { f16x8 v; f16x2 h[4]; } Uf;
                Uf.h[0] = pk2(fa.x, fa.y); Uf.h[1] = pk2(fa.z, fa.w);
                Uf.h[2] = pk2(fb.x, fb.y); Uf.h[3] = pk2(fb.z, fb.w);
                fH[u] = Uf.v;
            }
        }

        // ---- GEMM1: acc[u][c] = H[ch 16c+4g+r][point n], K = 224 ----------
        f32x4 acc[2][4];
        #pragma unroll
        for (int u = 0; u < 2; ++u)
            #pragma unroll
            for (int c = 0; c < 4; ++c)
                acc[u][c] = (f32x4){0.0f, 0.0f, 0.0f, 0.0f};

        #pragma unroll
        for (int s = 0; s < 7; ++s) {
            f16x8 U[2];
            const int k0 = s * 32 + g * 8;
            if (s == 0 && g < 2) {               // feats (pre-packed)
                U[0] = fH[0]; U[1] = fH[1];
            } else if (k0 >= 208) {              // zero pad (s==6, g>=2)
                union { f16x8 v; f16x2 h[4]; } Z;
                #pragma unroll
                for (int q = 0; q < 4; ++q) Z.h[q] = pk2(0.0f, 0.0f);
                U[0] = Z.v; U[1] = Z.v;
            } else {                             // PE: sin with phase in FMA chain
                const int   e    = k0 - 16;      // s==0,g>=2 -> e in {0,8}
                const float off  = (e & 32) ? PI2 : 0.0f;
                const float offc = (e & 32) ? (PI2 * (1.0f - RSTEP)) : 0.0f;
                #pragma unroll
                for (int u = 0; u < 2; ++u) {
                    const float pv = (e < 64) ? px[u] : ((e < 128) ? py[u] : pz[u]);
                    float a = fmaf(pv, base, off);
                    union { f16x8 v; f16x2 h[4]; } G;
                    #pragma unroll
                    for (int q = 0; q < 4; ++q) {
                        float v0 = __sinf(a); a = fmaf(a, RSTEP, offc);
                        float v1 = __sinf(a); a = fmaf(a, RSTEP, offc);
                        G.h[q] = pk2(v0, v1);
                    }
                    U[u] = G.v;
                }
            }
            #pragma unroll
            for (int c = 0; c < 4; ++c) {
                f16x8 af = ((const f16x8*)WF)[(s * 4 + c) * 64 + lane];
                acc[0][c] = __builtin_amdgcn_mfma_f32_16x16x32_f16(af, U[0], acc[0][c], 0, 0, 0);
                acc[1][c] = __builtin_amdgcn_mfma_f32_16x16x32_f16(af, U[1], acc[1][c], 0, 0, 0);
            }
        }

        // ---- per tile: LN + GELU -> Pw, GEMM2, store ----------------------
        #pragma unroll
        for (int u = 0; u < 2; ++u) {
            char* Pwu = Pw + u * 2048;

            // LN stats (lane-local 16 + 2 shuffles)
            float s1 = 0.0f, s2 = 0.0f;
            #pragma unroll
            for (int c = 0; c < 4; ++c) {
                f32x4 b1q = *(const f32x4*)(b1 + 16 * c + 4 * g);
                #pragma unroll
                for (int r = 0; r < 4; ++r) {
                    float x = acc[u][c][r] + b1q[r];
                    acc[u][c][r] = x;
                    s1 += x; s2 += x * x;
                }
            }
            s1 += __shfl_xor(s1, 16); s2 += __shfl_xor(s2, 16);
            s1 += __shfl_xor(s1, 32); s2 += __shfl_xor(s2, 32);
            const float mu   = s1 * (1.0f / 64.0f);
            const float var  = s2 * (1.0f / 64.0f) - mu * mu;
            const float rstd = __builtin_amdgcn_rsqf(var + 1e-5f);

            // GELU -> Pwu (b64 swizzled writes)
            #pragma unroll
            for (int c = 0; c < 4; ++c) {
                f32x4 gq = *(const f32x4*)(ln_g + 16 * c + 4 * g);
                f32x4 bq = *(const f32x4*)(ln_b + 16 * c + 4 * g);
                float gv[4];
                #pragma unroll
                for (int r = 0; r < 4; ++r) {
                    float x  = (acc[u][c][r] - mu) * rstd * gq[r] + bq[r];
                    float w  = x * (0.7978845608028654f + 0.0356774081363001f * x * x);
                    float e2 = __expf(2.0f * w);
                    float th = 1.0f - 2.0f * __builtin_amdgcn_rcpf(e2 + 1.0f);
                    gv[r] = 0.5f * x * (1.0f + th);
                }
                union { f16x2 h[2]; uint2 u2; } W;
                W.h[0] = pk2(gv[0], gv[1]);
                W.h[1] = pk2(gv[2], gv[3]);
                *(uint2*)(Pwu + n * 128 + (((unsigned)(32 * c + 8 * g)) ^ sw)) = W.u2;
            }

            // GEMM2: acc2[c] = O[ch 16c+4g+r][point n]
            f32x4 acc2[4];
            #pragma unroll
            for (int c = 0; c < 4; ++c) acc2[c] = (f32x4){0.0f, 0.0f, 0.0f, 0.0f};
            #pragma unroll
            for (int s = 0; s < 2; ++s) {
                f16x8 bf2 = *(const f16x8*)(Pwu + n * 128 + (((unsigned)(64 * s + 16 * g)) ^ sw));
                #pragma unroll
                for (int c = 0; c < 4; ++c) {
                    f16x8 af = ((const f16x8*)WF)[(W1_FRAGS + s * 4 + c) * 64 + lane];
                    acc2[c] = __builtin_amdgcn_mfma_f32_16x16x32_f16(af, bf2, acc2[c], 0, 0, 0);
                }
            }

            if (use_feat) {
                // stage D2 -> Pwu (b64 swizzled), then full-line scattered stores
                #pragma unroll
                for (int c = 0; c < 4; ++c) {
                    union { f16x2 h[2]; uint2 u2; } W;
                    W.h[0] = pk2(acc2[c][0], acc2[c][1]);
                    W.h[1] = pk2(acc2[c][2], acc2[c][3]);
                    *(uint2*)(Pwu + n * 128 + (((unsigned)(32 * c + 8 * g)) ^ sw)) = W.u2;
                }
                // 8 lanes per row x 16B: each store instr covers full 128B lines
                #pragma unroll
                for (int h = 0; h < 2; ++h) {
                    const int row = h * 8 + (lane >> 3);
                    const int gs  = wbase + (tp * 2 + u) * 16 + row;
                    if (gs < NPTS) {
                        const uint4 v = *(const uint4*)(Pwu + row * 128 +
                            (((unsigned)((lane & 7) * 16)) ^ ((unsigned)((row & 7) << 4))));
                        *(uint4*)(featbuf + (size_t)rank[gs] * COUT + (lane & 7) * 8) = v;
                    }
                }
            } else {
                // fallback: direct fp32 atomics (correctness path, not perf)
                const int st = wbase + (tp * 2 + u) * 16 + n;
                if (st < NPTS) {
                    const int cellr = flat_of(pos, st, ax1p[0], ax2p[0]);
                    #pragma unroll
                    for (int c = 0; c < 4; ++c)
                        #pragma unroll
                        for (int r = 0; r < 4; ++r)
                            unsafeAtomicAdd(&out[(size_t)(16 * c + 4 * g + r) * NCELL + cellr],
                                            acc2[c][r]);
                }
            }
        }
    }
}

// K4: per-cell dense reduce. 1 cell per wave, 4 predicated independent loads
// (no serial tail); block = 1024 thr = 16 waves = 16 cells; 4096 blocks.
__global__ __launch_bounds__(1024)
void reduce_kernel(const _Float16* __restrict__ featbuf,
                   const unsigned int* __restrict__ starts,
                   const unsigned int* __restrict__ hist,
                   const float* __restrict__ b2,
                   float* __restrict__ out)
{
    __shared__ float R[16][66];
    const int lane  = threadIdx.x & 63;
    const int wv    = threadIdx.x >> 6;    // 0..15 = cell-within-block
    const int cbase = blockIdx.x * 16;
    const float b2v = b2[lane];

    const int cell = cbase + wv;
    const unsigned int s0  = starts[cell];
    const unsigned int cnt = hist[cell];

    float a0 = 0.0f, a1 = 0.0f, a2 = 0.0f, a3 = 0.0f;
    for (unsigned int k = 0; k < cnt; k += 4) {
        unsigned int i0 = s0 + k;
        unsigned int i1 = i0 + 1 < (unsigned)NPTS ? i0 + 1 : (unsigned)(NPTS - 1);
        unsigned int i2 = i0 + 2 < (unsigned)NPTS ? i0 + 2 : (unsigned)(NPTS - 1);
        unsigned int i3 = i0 + 3 < (unsigned)NPTS ? i0 + 3 : (unsigned)(NPTS - 1);
        float v0 = (float)featbuf[(size_t)i0 * COUT + lane];
        float v1 = (float)featbuf[(size_t)i1 * COUT + lane];
        float v2 = (float)featbuf[(size_t)i2 * COUT + lane];
        float v3 = (float)featbuf[(size_t)i3 * COUT + lane];
        a0 += v0;
        a1 += (k + 1 < cnt) ? v1 : 0.0f;
        a2 += (k + 2 < cnt) ? v2 : 0.0f;
        a3 += (k + 3 < cnt) ? v3 : 0.0f;
    }
    float m = (a0 + a1) + (a2 + a3);
    R[wv][lane] = m / fmaxf((float)cnt, 1.0f) + (cnt ? b2v : 0.0f);
    __syncthreads();

    // store: thread t -> out[ch = t>>4][cbase + (t&15)]; 64B contiguous per ch
    const int ch = threadIdx.x >> 4;
    const int ci = threadIdx.x & 15;
    out[ch * NCELL + cbase + ci] = R[ci][ch];
}

// K5 (fallback only): divide by counts + add b2 (guarded for empty cells)
__global__ void finalize_kernel(float* __restrict__ out,
                                const unsigned int* __restrict__ hist,
                                const float* __restrict__ b2)
{
    int t = blockIdx.x * 256 + threadIdx.x;
    int cell = t & (NCELL - 1);
    int ch   = t >> 16;
    float c  = (float)hist[cell];
    out[t] = out[t] / fmaxf(c, 1.0f) + ((c > 0.0f) ? b2[ch] : 0.0f);
}

extern "C" void kernel_launch(void* const* d_in, const int* in_sizes, int n_in,
                              void* d_out, int out_size, void* d_ws, size_t ws_size,
                              hipStream_t stream) {
    (void)in_sizes; (void)n_in; (void)out_size;
    const float* pos   = (const float*)d_in[0];
    const float* feats = (const float*)d_in[1];
    const float* W1    = (const float*)d_in[2];
    const float* b1    = (const float*)d_in[3];
    const float* ln_g  = (const float*)d_in[4];
    const float* ln_b  = (const float*)d_in[5];
    const float* W2    = (const float*)d_in[6];
    const float* b2    = (const float*)d_in[7];
    const int*   ax1   = (const int*)d_in[8];
    const int*   ax2   = (const int*)d_in[9];

    char* ws = (char*)d_ws;
    unsigned int*   hist   = (unsigned int*)(ws + WS_HIST);
    unsigned int*   cur    = (unsigned int*)(ws + WS_CUR);
    unsigned int*   starts = (unsigned int*)(ws + WS_STARTS);
    int*            rank   = (int*)(ws + WS_RANK);
    _Float16*       wpk    = (_Float16*)(ws + WS_WPK);
    unsigned int*   part   = (unsigned int*)(ws + WS_PART);
    _Float16*       featbf = (_Float16*)(ws + WS_FEAT);
    unsigned short* cell16 = (unsigned short*)(ws + WS_FEAT);  // overlay, pre-mlp

    float* out = (float*)d_out;
    const int use_feat = (ws_size >= WS_NEED) ? 1 : 0;

    hipMemsetAsync(hist, 0, NCELL * sizeof(unsigned int), stream);
    if (!use_feat)
        hipMemsetAsync(d_out, 0, (size_t)COUT * NCELL * sizeof(float), stream);

    pack_hist_kernel<<<PT_BLOCKS, 256, 0, stream>>>(
        W1, W2, pos, ax1, ax2, wpk, hist,
        use_feat ? cell16 : (unsigned short*)nullptr);
    if (use_feat) {
        scan_sum_kernel<<<256, 256, 0, stream>>>(hist, part);
        scan_top_kernel<<<1, 256, 0, stream>>>(part);
        scan_apply_kernel<<<256, 256, 0, stream>>>(hist, part, cur, starts);
        scatter_kernel<<<PT_BLOCKS, 256, 0, stream>>>(cell16, cur, rank);
    }
    mlp_mfma_kernel<<<MB_BLOCKS, 512, 0, stream>>>(
        pos, feats, wpk, b1, ln_g, ln_b, ax1, ax2, rank, featbf, out, use_feat);
    if (use_feat)
        reduce_kernel<<<NCELL / 16, 1024, 0, stream>>>(featbf, starts, hist, b2, out);
    else
        finalize_kernel<<<(COUT * NCELL) / 256, 256, 0, stream>>>(out, hist, b2);
}